// Round 10
// baseline (189.035 us; speedup 1.0000x reference)
//
#include <hip/hip_runtime.h>
#include <math.h>

// Problem constants
constexpr int NROI = 2048;  // N
constexpr int CDIM = 1024;  // C
constexpr int NG   = 16;    // groups
constexpr int DH   = 64;    // per-group dim

typedef __attribute__((ext_vector_type(8))) short short8;    // 8 bf16 (4 VGPRs)
typedef __attribute__((ext_vector_type(4))) float floatx4;   // MFMA C/D frag

#define MFMA_BF16(a, b, c) __builtin_amdgcn_mfma_f32_16x16x32_bf16((a), (b), (c), 0, 0, 0)

// fp32 -> bf16 round-to-nearest-even
__device__ __forceinline__ short f2bf(float f) {
  unsigned u = __float_as_uint(f);
  unsigned r = 0x7fffu + ((u >> 16) & 1u);
  return (short)((u + r) >> 16);
}
__device__ __forceinline__ float bf2f(unsigned short u) {
  return __uint_as_float(((unsigned)u) << 16);
}
__device__ __forceinline__ unsigned pack2(float a, float b) {
  return (unsigned)(unsigned short)f2bf(a) | ((unsigned)(unsigned short)f2bf(b) << 16);
}

// async global->LDS, 16B per lane; LDS dest = wave-uniform base + lane*16
typedef __attribute__((address_space(1))) void GV;
typedef __attribute__((address_space(3))) void LV;
__device__ __forceinline__ void gl2lds16(const void* g, void* l) {
  __builtin_amdgcn_global_load_lds((GV*)g, (LV*)l, 16, 0, 0);
}

// bf16 relu on a packed short8 (sign-bit based; exact)
__device__ __forceinline__ short8 brelu(short8 v) {
  union { short8 s; unsigned u[4]; } x; x.s = v;
#pragma unroll
  for (int i = 0; i < 4; ++i) {
    unsigned m = (x.u[i] >> 15) & 0x10001u;
    x.u[i] &= ~(m * 0xFFFFu);
  }
  return x.s;
}

// ---------------- streaming fp32 -> bf16 conversion (x + 3 weights) ----------------
__global__ __launch_bounds__(256) void convert_kernel(
    const float* __restrict__ in_x, const float* __restrict__ W0,
    const float* __restrict__ W1, const float* __restrict__ Wout,
    short* __restrict__ xin_b, short* __restrict__ W0b,
    short* __restrict__ W1b, short* __restrict__ Woutb)
{
  const int i = blockIdx.x * 256 + threadIdx.x;   // float4 units
  {
    const float4 v = ((const float4*)in_x)[i];
    uint2 u; u.x = pack2(v.x, v.y); u.y = pack2(v.z, v.w);
    ((uint2*)xin_b)[i] = u;
  }
  if (i < 262144) {
    float4 v = ((const float4*)W0)[i];
    uint2 u; u.x = pack2(v.x, v.y); u.y = pack2(v.z, v.w);
    ((uint2*)W0b)[i] = u;
    v = ((const float4*)W1)[i];
    u.x = pack2(v.x, v.y); u.y = pack2(v.z, v.w);
    ((uint2*)W1b)[i] = u;
    v = ((const float4*)Wout)[i];
    u.x = pack2(v.x, v.y); u.y = pack2(v.z, v.w);
    ((uint2*)Woutb)[i] = u;
  }
}

// ---------------- iou+1e-6 matrix, 4 keys/thread, rcp divide, 8-B stores ----------------
__global__ __launch_bounds__(256) void iou4_kernel(const float* __restrict__ rois,
                                                   unsigned short* __restrict__ biasb)
{
  const int q  = blockIdx.y;
  const int k0 = (blockIdx.x * 256 + threadIdx.x) * 4;
  const float qx1 = rois[q * 5 + 1], qy1 = rois[q * 5 + 2];
  const float qx2 = rois[q * 5 + 3], qy2 = rois[q * 5 + 4];
  const float qa = (qx2 - qx1 + 1.f) * (qy2 - qy1 + 1.f);
  float v[4];
#pragma unroll
  for (int j = 0; j < 4; ++j) {
    const int k = k0 + j;
    const float kx1 = rois[k * 5 + 1], ky1 = rois[k * 5 + 2];
    const float kx2 = rois[k * 5 + 3], ky2 = rois[k * 5 + 4];
    const float ka = (kx2 - kx1 + 1.f) * (ky2 - ky1 + 1.f);
    float iw = fminf(qx2, kx2) - fmaxf(qx1, kx1) + 1.f;
    float ih = fminf(qy2, ky2) - fmaxf(qy1, ky1) + 1.f;
    iw = fmaxf(iw, 0.f); ih = fmaxf(ih, 0.f);
    const float inter = iw * ih;
    v[j] = inter * __builtin_amdgcn_rcpf(qa + ka - inter) + 1e-6f;
  }
  uint2 u; u.x = pack2(v[0], v[1]); u.y = pack2(v[2], v[3]);
  *(uint2*)&biasb[(size_t)q * NROI + k0] = u;
}

// ---------------- 64x64 double-buffered GEMM + XCD-region swizzle ----------------
// FUSED=1: col-blocks 0..15 -> t0 = relu(x)@W0^T+b0 (row-major); 16..31 ->
//          zT = (x@Wout^T)^T. grid (32,32). FUSED=0: C = relu(A)@B^T + bias, grid (16,32).
// Swizzle: linear block id L -> xcd = L&7 (HW round-robin heuristic); each XCD
// gets a contiguous (cols x rows) region so its working set (A-stripes +
// B-stripes) fits the 4 MB per-XCD L2 -> tile re-reads become L2 hits instead
// of L3 round-trips (inter-dispatch L2 invalidation makes every launch cold).
template <int FUSED>
__global__ __launch_bounds__(256, 4) void gemm64(
    const short* __restrict__ A, const short* __restrict__ Ba,
    const short* __restrict__ Bb, const float* __restrict__ bias,
    short* __restrict__ outRM, short* __restrict__ outTR)
{
  __shared__ short As[2][8 * 512];
  __shared__ short Bs[2][8 * 512];
  const int t = threadIdx.x, w = t >> 6, lane = t & 63;
  const int wm = w >> 1, wn = w & 1;

  // XCD-region swizzle
  int bxr, byr;
  {
    const int L = blockIdx.y * gridDim.x + blockIdx.x;
    const int xcd = L & 7;
    const int i = L >> 3;
    if (FUSED) {          // grid 32x32 -> regions 8 cols x 16 rows
      bxr = (xcd & 3) * 8 + (i & 7);
      byr = (xcd >> 2) * 16 + (i >> 3);
    } else {              // grid 16x32 -> regions 4 cols x 16 rows
      bxr = (xcd & 3) * 4 + (i & 3);
      byr = (xcd >> 2) * 16 + (i >> 2);
    }
  }
  const int row0 = byr * 64;
  bool isW0; int col0; const short* B;
  if (FUSED) {
    isW0 = bxr < 16;
    col0 = (bxr & 15) * 64;
    B = isW0 ? Ba : Bb;
  } else {
    isW0 = true; col0 = bxr * 64; B = Ba;
  }
  const bool doRelu = FUSED ? isW0 : true;
  const int rlo = lane & 15, khi = (lane >> 4) * 8;

  floatx4 acc[2][2];
#pragma unroll
  for (int i = 0; i < 2; ++i)
#pragma unroll
    for (int j = 0; j < 2; ++j) acc[i][j] = (floatx4){0.f, 0.f, 0.f, 0.f};

#pragma unroll
  for (int kh = 0; kh < 2; ++kh) {
    const int f = w * 2 + kh;
    gl2lds16(A + (size_t)(row0 + w * 16 + rlo) * CDIM + kh * 32 + khi, &As[0][f * 512]);
    gl2lds16(B + (size_t)(col0 + w * 16 + rlo) * CDIM + kh * 32 + khi, &Bs[0][f * 512]);
  }
  __syncthreads();

  for (int it = 0; it < 16; ++it) {
    const int p = it & 1;
    if (it < 15) {
      const int k1 = (it + 1) * 64;
#pragma unroll
      for (int kh = 0; kh < 2; ++kh) {
        const int f = w * 2 + kh;
        gl2lds16(A + (size_t)(row0 + w * 16 + rlo) * CDIM + k1 + kh * 32 + khi,
                 &As[1 - p][f * 512]);
        gl2lds16(B + (size_t)(col0 + w * 16 + rlo) * CDIM + k1 + kh * 32 + khi,
                 &Bs[1 - p][f * 512]);
      }
    }
#pragma unroll
    for (int kh = 0; kh < 2; ++kh) {
      short8 a[2], bf[2];
#pragma unroll
      for (int i = 0; i < 2; ++i) {
        a[i] = *(const short8*)&As[p][((wm * 2 + i) * 2 + kh) * 512 + lane * 8];
        if (doRelu) a[i] = brelu(a[i]);
      }
#pragma unroll
      for (int j = 0; j < 2; ++j)
        bf[j] = *(const short8*)&Bs[p][((wn * 2 + j) * 2 + kh) * 512 + lane * 8];
#pragma unroll
      for (int i = 0; i < 2; ++i)
#pragma unroll
        for (int j = 0; j < 2; ++j)
          acc[i][j] = MFMA_BF16(a[i], bf[j], acc[i][j]);
    }
    __syncthreads();
  }

  const int colL = lane & 15, qq = lane >> 4;
  if (!FUSED || isW0) {
    float bj[2];
    bj[0] = bias[col0 + wn * 32 + colL];
    bj[1] = bias[col0 + wn * 32 + 16 + colL];
#pragma unroll
    for (int i = 0; i < 2; ++i)
#pragma unroll
      for (int j = 0; j < 2; ++j)
#pragma unroll
        for (int r = 0; r < 4; ++r) {
          const int row = row0 + wm * 32 + i * 16 + qq * 4 + r;
          const int cc  = col0 + wn * 32 + j * 16 + colL;
          outRM[(size_t)row * CDIM + cc] = f2bf(acc[i][j][r] + bj[j]);
        }
  } else {
#pragma unroll
    for (int i = 0; i < 2; ++i)
#pragma unroll
      for (int j = 0; j < 2; ++j) {
        unsigned long long u =
            (unsigned long long)pack2(acc[i][j][0], acc[i][j][1]) |
            ((unsigned long long)pack2(acc[i][j][2], acc[i][j][3]) << 32);
        const int cc  = col0 + wn * 32 + j * 16 + colL;
        const int row = row0 + wm * 32 + i * 16 + qq * 4;
        *(unsigned long long*)&outTR[(size_t)cc * NROI + row] = u;
      }
  }
}

// ---------------- MFMA flash attention (R3-verified, verbatim — control) ----------------
__global__ __launch_bounds__(512) void attn_bias(
    const short* __restrict__ Xb,             // (N,C) bf16 embedded x
    const short* __restrict__ ZTb,            // (C,N) bf16 V, transposed
    const unsigned short* __restrict__ biasb, // (N,N) bf16 iou+1e-6
    const float* __restrict__ bout,
    float* __restrict__ Out)
{
  const int g  = blockIdx.y;
  const int n0 = blockIdx.x * 128;
  const int t  = threadIdx.x;
  const int w    = t >> 6;
  const int lane = t & 63;
  const int col  = lane & 15;
  const int qq   = lane >> 4;
  const int t16 = (w >> 1) * 16;
  const int h32 = (w & 1) * 32;
  const int rlo = lane & 15, khi = (lane >> 4) * 8;

  __shared__ short Kf[2][8 * 512];
  __shared__ short Vf[2][8 * 512];
  __shared__ short Pf[8 * 1024];

  const size_t qoff = (size_t)(n0 + w * 16 + col) * CDIM + g * DH;
  const short8 qf0 = *(const short8*)(Xb + qoff + qq * 8);
  const short8 qf1 = *(const short8*)(Xb + qoff + 32 + qq * 8);

  floatx4 oc[4];
#pragma unroll
  for (int dt = 0; dt < 4; ++dt) oc[dt] = (floatx4){0.f, 0.f, 0.f, 0.f};
  float lsum[4] = {0.f, 0.f, 0.f, 0.f};

  gl2lds16(Xb + (size_t)(t16 + rlo) * CDIM + g * DH + h32 + khi, &Kf[0][w * 512]);
  gl2lds16(ZTb + (size_t)(g * DH + t16 + rlo) * NROI + h32 + khi, &Vf[0][w * 512]);
  __syncthreads();

  for (int it = 0; it < NROI / 64; ++it) {
    const int p  = it & 1;
    const int m0 = it * 64;
    if (it + 1 < NROI / 64) {
      const int m1 = m0 + 64;
      gl2lds16(Xb + (size_t)(m1 + t16 + rlo) * CDIM + g * DH + h32 + khi,
               &Kf[1 - p][w * 512]);
      gl2lds16(ZTb + (size_t)(g * DH + t16 + rlo) * NROI + m1 + h32 + khi,
               &Vf[1 - p][w * 512]);
    }

    float bb[4][4];
#pragma unroll
    for (int ct = 0; ct < 4; ++ct)
#pragma unroll
      for (int r = 0; r < 4; ++r)
        bb[ct][r] = bf2f(biasb[(size_t)(n0 + w * 16 + qq * 4 + r) * NROI +
                               m0 + ct * 16 + col]);

    floatx4 sc[4];
#pragma unroll
    for (int ct = 0; ct < 4; ++ct) {
      const short8 b0 = *(const short8*)&Kf[p][(ct * 2 + 0) * 512 + lane * 8];
      const short8 b1 = *(const short8*)&Kf[p][(ct * 2 + 1) * 512 + lane * 8];
      floatx4 z4 = (floatx4){0.f, 0.f, 0.f, 0.f};
      z4 = MFMA_BF16(qf0, b0, z4);
      z4 = MFMA_BF16(qf1, b1, z4);
      sc[ct] = z4;
    }

#pragma unroll
    for (int ct = 0; ct < 4; ++ct)
#pragma unroll
      for (int r = 0; r < 4; ++r)
        sc[ct][r] = __expf(sc[ct][r] * 0.125f) * bb[ct][r];
#pragma unroll
    for (int r = 0; r < 4; ++r)
      lsum[r] += sc[0][r] + sc[1][r] + sc[2][r] + sc[3][r];

    {
      short* pw = &Pf[w * 1024];
#pragma unroll
      for (int ct = 0; ct < 4; ++ct) {
        const int key = ct * 16 + col;
        const int base = (key >> 5) * 512 + (key & 7);
#pragma unroll
        for (int r = 0; r < 4; ++r) {
          const int dl = (4 * qq + r) + ((key >> 3) & 3) * 16;
          pw[base + dl * 8] = f2bf(sc[ct][r]);
        }
      }
      const short8 pa0 = *(const short8*)&pw[0 * 512 + lane * 8];
      const short8 pa1 = *(const short8*)&pw[1 * 512 + lane * 8];
#pragma unroll
      for (int dt = 0; dt < 4; ++dt) {
        const short8 v0 = *(const short8*)&Vf[p][(dt * 2 + 0) * 512 + lane * 8];
        const short8 v1 = *(const short8*)&Vf[p][(dt * 2 + 1) * 512 + lane * 8];
        oc[dt] = MFMA_BF16(pa0, v0, oc[dt]);
        oc[dt] = MFMA_BF16(pa1, v1, oc[dt]);
      }
    }
    __syncthreads();
  }

#pragma unroll
  for (int r = 0; r < 4; ++r) {
    float s = lsum[r];
    s += __shfl_xor(s, 1); s += __shfl_xor(s, 2);
    s += __shfl_xor(s, 4); s += __shfl_xor(s, 8);
    lsum[r] = s;
  }
#pragma unroll
  for (int dt = 0; dt < 4; ++dt) {
    const float bo = bout[g * DH + dt * 16 + col];
#pragma unroll
    for (int r = 0; r < 4; ++r)
      Out[(size_t)(n0 + w * 16 + qq * 4 + r) * CDIM + g * DH + dt * 16 + col] =
          oc[dt][r] / lsum[r] + bo;
  }
}

extern "C" void kernel_launch(void* const* d_in, const int* in_sizes, int n_in,
                              void* d_out, int out_size, void* d_ws, size_t ws_size,
                              hipStream_t stream) {
  const float* in_x = (const float*)d_in[0];
  const float* rois = (const float*)d_in[1];
  const float* W0   = (const float*)d_in[2];
  const float* b0   = (const float*)d_in[3];
  const float* W1   = (const float*)d_in[4];
  const float* b1   = (const float*)d_in[5];
  const float* Wout = (const float*)d_in[6];  // (G,D,C) flat == (C,C) row-major
  const float* bout = (const float*)d_in[7];
  char* w8 = (char*)d_ws;

  // ws layout (22 MB):
  //   [0,4M)   xin_b (bf16 x) -> xb (gemm1 out; xin_b dead after gemm64<1>)
  //   [4,6M)   W0b   [6,8M) W1b   [8,10M) Woutb
  //   [10,14M) zT (bf16 V^T)
  //   [14,22M) biasb (bf16 iou+1e-6)
  // t0b (bf16 gemm0 out) lives in d_out; attn overwrites d_out with final fp32.
  short* xin_b = (short*)w8;
  short* W0b   = (short*)(w8 + ((size_t)4 << 20));
  short* W1b   = (short*)(w8 + ((size_t)6 << 20));
  short* Woutb = (short*)(w8 + ((size_t)8 << 20));
  short* zT    = (short*)(w8 + ((size_t)10 << 20));
  unsigned short* biasb = (unsigned short*)(w8 + ((size_t)14 << 20));
  short* xb  = xin_b;
  short* t0b = (short*)d_out;

  // 1) streaming converts
  convert_kernel<<<2048, 256, 0, stream>>>(in_x, W0, W1, Wout,
                                           xin_b, W0b, W1b, Woutb);
  // 2) iou bias matrix
  iou4_kernel<<<dim3(2, NROI), 256, 0, stream>>>(rois, biasb);
  // 3) fused 64x64 + XCD swizzle: t0 = relu(x)@W0^T+b0 and zT = (x@Wout^T)^T
  gemm64<1><<<dim3(32, 32), 256, 0, stream>>>(xin_b, W0b, Woutb, b0, t0b, zT);
  // 4) 64x64 + XCD swizzle: xb = relu(t0)@W1^T + b1
  gemm64<0><<<dim3(16, 32), 256, 0, stream>>>(t0b, W1b, nullptr, b1, xb, nullptr);
  // 5) flash attention (R3-verified, control)
  attn_bias<<<dim3(NROI / 128, NG), 512, 0, stream>>>(xb, zT, biasb, bout,
                                                      (float*)d_out);
}